// Round 5
// baseline (1906.633 us; speedup 1.0000x reference)
//
#include <hip/hip_runtime.h>
#include <math.h>

// ---------------- problem constants ----------------
#define NN   32
#define CC   128
#define TT   400
#define VV   27
#define SS   2
#define ICC  32
#define RCC  32
#define TVV  (TT * VV)            // 10800
#define EPSF 1e-5f

static constexpr size_t CTV = (size_t)CC * TVV;      // 1,382,400
static constexpr size_t FSZ = (size_t)NN * CTV;      // 44,236,800
static constexpr size_t F4  = (size_t)NN * RCC * TVV;// 11,059,200

// ---------------- workspace layout (floats) ----------------
static constexpr size_t OFF_PE      = 0;        // 3456
static constexpr size_t OFF_WT_IN   = 4096;     // 16384   in_w^T [c][o]
static constexpr size_t OFF_WS_OUT  = 20480;    // 32768   out_w scaled, [c][s*128+o]
static constexpr size_t OFF_B_OUT   = 53248;    // 128
static constexpr size_t OFF_WT_FF   = 53632;    // 16384   ff_w^T scaled [c][o]
static constexpr size_t OFF_B_FF    = 70016;    // 128
static constexpr size_t OFF_WT_DOWN = 70144;    // 4096    down_w^T scaled [c][o2]
static constexpr size_t OFF_B_DOWN  = 74240;    // 32
static constexpr size_t OFF_DWS     = 74272;    // 288     dw_w scaled
static constexpr size_t OFF_DBS     = 74560;    // 96
static constexpr size_t OFF_PWS     = 74656;    // 3072    pw_w scaled
static constexpr size_t OFF_BSUM    = 77728;    // 32
static constexpr size_t OFF_WT_BACK = 77760;    // 4096    back_w^T scaled [k][o]
static constexpr size_t OFF_B_BACK  = 81856;    // 128
static constexpr size_t OFF_ATT     = 81984;    // 46656   [n][s][u][v]
static constexpr size_t OFF_ATTP    = 128640;   // 8*46656 partial gram
static constexpr size_t OFF_BUFA    = 501888;   // FSZ   (qk, then y2)
static constexpr size_t OFF_YD      = OFF_BUFA + FSZ;  // F4

// ---------------- prep: pe table + transposed / BN-folded weights ----------------
__global__ void prep_k(const float* __restrict__ in_w,
                       const float* __restrict__ out_w, const float* __restrict__ out_b,
                       const float* __restrict__ out_bn,
                       const float* __restrict__ ff_w, const float* __restrict__ ff_b,
                       const float* __restrict__ ff_bn,
                       const float* __restrict__ down_w, const float* __restrict__ down_bn,
                       const float* __restrict__ dw_w, const float* __restrict__ dw_b,
                       const float* __restrict__ bn_a,
                       const float* __restrict__ pw_w, const float* __restrict__ bn_b,
                       const float* __restrict__ back_w, const float* __restrict__ back_bn,
                       float* __restrict__ ws)
{
  const int gid = blockIdx.x * blockDim.x + threadIdx.x;
  const int nth = gridDim.x * blockDim.x;
  const float rs = rsqrtf(1.f + EPSF);

  for (int i = gid; i < CC * VV; i += nth) {
    const int c = i / VV, v = i % VV;
    const int h = c >> 1;
    const float div = expf((float)(2 * h) * (-logf(10000.f) / (float)CC));
    const float ang = (float)v * div;
    ws[OFF_PE + i] = (c & 1) ? cosf(ang) : sinf(ang);
  }
  for (int i = gid; i < CC * CC; i += nth) {
    const int c = i >> 7, o = i & 127;
    ws[OFF_WT_IN + i] = in_w[o * CC + c];
  }
  // out_w split-transposed scaled: [c][m], m = s*128+o
  for (int i = gid; i < CC * 2 * CC; i += nth) {
    const int c = i >> 8, m = i & 255, o = m & 127, s = m >> 7;
    ws[OFF_WS_OUT + i] = out_w[o * (2 * CC) + s * CC + c] * (out_bn[o] * rs);
  }
  for (int i = gid; i < CC; i += nth) {
    const float s = out_bn[i] * rs;
    ws[OFF_B_OUT + i] = s * out_b[i] + out_bn[CC + i];
  }
  for (int i = gid; i < CC * CC; i += nth) {
    const int c = i >> 7, o = i & 127;
    ws[OFF_WT_FF + i] = ff_w[o * CC + c] * (ff_bn[o] * rs);
  }
  for (int i = gid; i < CC; i += nth) {
    const float s = ff_bn[i] * rs;
    ws[OFF_B_FF + i] = s * ff_b[i] + ff_bn[CC + i];
  }
  for (int i = gid; i < CC * RCC; i += nth) {
    const int c = i >> 5, o = i & 31;
    ws[OFF_WT_DOWN + i] = down_w[o * CC + c] * (down_bn[o] * rs);
  }
  for (int i = gid; i < RCC; i += nth) ws[OFF_B_DOWN + i] = down_bn[RCC + i];
  for (int i = gid; i < 3 * RCC * 3; i += nth) {
    const int b = i / 96, r = i % 96, c = r / 3;
    ws[OFF_DWS + i] = dw_w[i] * (bn_a[b * 64 + c] * rs);
  }
  for (int i = gid; i < 3 * RCC; i += nth) {
    const int b = i >> 5, c = i & 31;
    ws[OFF_DBS + i] = (bn_a[b * 64 + c] * rs) * dw_b[i] + bn_a[b * 64 + 32 + c];
  }
  for (int i = gid; i < 3 * RCC * RCC; i += nth) {
    const int b = i >> 10, o = (i & 1023) >> 5;
    ws[OFF_PWS + i] = pw_w[i] * (bn_b[b * 64 + o] * rs);
  }
  for (int i = gid; i < RCC; i += nth)
    ws[OFF_BSUM + i] = bn_b[32 + i] + bn_b[96 + i] + bn_b[160 + i];
  for (int i = gid; i < RCC * CC; i += nth) {
    const int k = i >> 7, o = i & 127;
    ws[OFF_WT_BACK + i] = back_w[o * RCC + k] * (back_bn[o] * rs);
  }
  for (int i = gid; i < CC; i += nth) ws[OFF_B_BACK + i] = back_bn[CC + i];
}

// ---------------- qk projection GEMM: qk[n][o][p] = in_w^T (x+pe) + in_b -----
__global__ __launch_bounds__(256, 4) void qkproj_k(
    const float* __restrict__ X, const float* __restrict__ wT,
    const float* __restrict__ bias, const float* __restrict__ pe,
    float* __restrict__ Y)
{
  __shared__ float Xs[32][68];
  __shared__ float Ws[32][132];
  const int n  = blockIdx.y;
  const int p0 = blockIdx.x * 64;
  const int tid = threadIdx.x;
  const int pg = tid & 15;
  const int og = tid >> 4;

  float acc[8][4];
#pragma unroll
  for (int i = 0; i < 8; ++i)
#pragma unroll
    for (int j = 0; j < 4; ++j) acc[i][j] = 0.f;

  const float* Xn = X + (size_t)n * CTV;

  for (int k0 = 0; k0 < CC; k0 += 32) {
    for (int sl = tid; sl < 512; sl += 256) {
      const int r  = sl >> 4;
      const int cc = (sl & 15) * 4;
      const int p  = p0 + cc;
      const float* src = Xn + (size_t)(k0 + r) * TVV;
      float4 val;
      if (p + 3 < TVV) {
        val = *(const float4*)(src + p);
      } else {
        val.x = (p     < TVV) ? src[p]     : 0.f;
        val.y = (p + 1 < TVV) ? src[p + 1] : 0.f;
        val.z = (p + 2 < TVV) ? src[p + 2] : 0.f;
        val.w = (p + 3 < TVV) ? src[p + 3] : 0.f;
      }
      const float* per = pe + (size_t)(k0 + r) * VV;
      val.x += per[p % VV];
      val.y += per[(p + 1) % VV];
      val.z += per[(p + 2) % VV];
      val.w += per[(p + 3) % VV];
      *(float4*)&Xs[r][cc] = val;
    }
    for (int q = tid; q < 1024; q += 256) {
      const int r = q >> 5, c4 = (q & 31) * 4;
      *(float4*)&Ws[r][c4] = *(const float4*)(wT + (size_t)(k0 + r) * CC + c4);
    }
    __syncthreads();
#pragma unroll 8
    for (int k = 0; k < 32; ++k) {
      const float4 xv = *(const float4*)&Xs[k][pg * 4];
      const float4 wA = *(const float4*)&Ws[k][og * 8];
      const float4 wB = *(const float4*)&Ws[k][og * 8 + 4];
      const float wv[8] = {wA.x, wA.y, wA.z, wA.w, wB.x, wB.y, wB.z, wB.w};
#pragma unroll
      for (int i = 0; i < 8; ++i) {
        acc[i][0] = fmaf(wv[i], xv.x, acc[i][0]);
        acc[i][1] = fmaf(wv[i], xv.y, acc[i][1]);
        acc[i][2] = fmaf(wv[i], xv.z, acc[i][2]);
        acc[i][3] = fmaf(wv[i], xv.w, acc[i][3]);
      }
    }
    __syncthreads();
  }

  const int pcol = p0 + pg * 4;
#pragma unroll
  for (int i = 0; i < 8; ++i) {
    const int o = og * 8 + i;
    const float bv = bias[o];
    const size_t rowoff = (size_t)n * CTV + (size_t)o * TVV;
    if (pcol + 3 < TVV) {
      float4 st;
      st.x = acc[i][0] + bv; st.y = acc[i][1] + bv;
      st.z = acc[i][2] + bv; st.w = acc[i][3] + bv;
      *(float4*)(Y + rowoff + pcol) = st;
    } else {
#pragma unroll
      for (int j = 0; j < 4; ++j) {
        const int p = pcol + j;
        if (p < TVV) Y[rowoff + p] = acc[i][j] + bv;
      }
    }
  }
}

// ---------------- attention gram partials ----------------
__global__ __launch_bounds__(256) void attpart_k(
    const float* __restrict__ qk, float* __restrict__ attP)
{
  __shared__ float qs[270], ks[270];
  const int ns  = blockIdx.x;
  const int seg = blockIdx.y;
  const int n = ns >> 1, s = ns & 1;
  const int tid = threadIdx.x;
  const float* qb = qk + (size_t)n * CTV + (size_t)(s * ICC) * TVV;
  const float* kb = qk + (size_t)n * CTV + (size_t)((SS + s) * ICC) * TVV;
  const int p0 = tid, p1 = tid + 256, p2 = tid + 512;
  const int u0 = p0 / VV, v0 = p0 % VV;
  const int u1 = p1 / VV, v1 = p1 % VV;
  const int u2 = p2 / VV, v2 = p2 % VV;
  float a0 = 0.f, a1 = 0.f, a2 = 0.f;
  for (int c = 0; c < ICC; ++c) {
    const float* qrow = qb + (size_t)c * TVV;
    const float* krow = kb + (size_t)c * TVV;
    for (int t0 = seg * 50; t0 < seg * 50 + 50; t0 += 10) {
      for (int idx = tid; idx < 270; idx += 256) {
        qs[idx] = qrow[t0 * VV + idx];
        ks[idx] = krow[t0 * VV + idx];
      }
      __syncthreads();
#pragma unroll
      for (int tt = 0; tt < 10; ++tt) {
        const float* qr = &qs[tt * VV];
        const float* kr = &ks[tt * VV];
        a0 = fmaf(qr[u0], kr[v0], a0);
        a1 = fmaf(qr[u1], kr[v1], a1);
        if (p2 < 729) a2 = fmaf(qr[u2], kr[v2], a2);
      }
      __syncthreads();
    }
  }
  float* dst = attP + (size_t)seg * (NN * SS * VV * VV) + (size_t)ns * (VV * VV);
  dst[p0] = a0;
  dst[p1] = a1;
  if (p2 < 729) dst[p2] = a2;
}

__global__ void attfin_k(const float* __restrict__ attP,
                         const float* __restrict__ alphas,
                         const float* __restrict__ att0,
                         float* __restrict__ att)
{
  const int idx = blockIdx.x * 256 + threadIdx.x;
  if (idx >= NN * SS * VV * VV) return;
  float m = 0.f;
#pragma unroll
  for (int g = 0; g < 8; ++g) m += attP[(size_t)g * (NN * SS * VV * VV) + idx];
  const int s  = (idx / (VV * VV)) & 1;
  const int uv = idx % (VV * VV);
  att[idx] = tanhf(m * (1.f / (ICC * TT))) * alphas[s] + att0[s * VV * VV + uv];
}

// ---------------- zmix: z = W'@x (256 out) fused with attention mix ----------
//   y1 = lrelu(x + bO + sum_s z_s @ att_s)   written to d_out
// tile: 256m x 108p (4 t), 576 threads, thread tile 8m x 6p.
__global__ __launch_bounds__(576, 4) void zmix_k(
    const float* __restrict__ x, const float* __restrict__ wT,
    const float* __restrict__ att, const float* __restrict__ bO,
    float* __restrict__ y1)
{
  __shared__ float SM[14848];           // GEMM: Xs[32][112]@0, Ws[32][260]@3584 | mix: zs[256][58]@0
  __shared__ float as[SS * VV * 28];    // as[s][u][v], stride 28
  const int n   = blockIdx.y;
  const int p0  = blockIdx.x * 108;
  const int tid = threadIdx.x;

  for (int i = tid; i < SS * VV * VV; i += 576) {
    const int s = i / (VV * VV), uv = i % (VV * VV);
    as[s * VV * 28 + (uv / VV) * 28 + (uv % VV)] = att[(size_t)n * (SS * VV * VV) + i];
  }

  const int og = tid / 18;              // 0..31 -> m = og*8+i
  const int pg = tid % 18;              // 0..17 -> p = pg*6+j

  float acc[8][6];
#pragma unroll
  for (int i = 0; i < 8; ++i)
#pragma unroll
    for (int j = 0; j < 6; ++j) acc[i][j] = 0.f;

  const float* Xn = x + (size_t)n * CTV;
  float* Xs = SM;                       // stride 112
  float* Ws = SM + 3584;                // stride 260

  for (int k0 = 0; k0 < CC; k0 += 32) {
    for (int q = tid; q < 864; q += 576) {
      const int r = q / 27, c4 = (q % 27) * 4;
      *(float4*)&Xs[r * 112 + c4] =
          *(const float4*)(Xn + (size_t)(k0 + r) * TVV + p0 + c4);
    }
    for (int q = tid; q < 2048; q += 576) {
      const int r = q >> 6, c4 = (q & 63) * 4;
      *(float4*)&Ws[r * 260 + c4] = *(const float4*)(wT + (size_t)(k0 + r) * 256 + c4);
    }
    __syncthreads();
#pragma unroll 4
    for (int k = 0; k < 32; ++k) {
      const float* xr = &Xs[k * 112 + pg * 6];
      const float2 x01 = *(const float2*)(xr);
      const float2 x23 = *(const float2*)(xr + 2);
      const float2 x45 = *(const float2*)(xr + 4);
      const float xv[6] = {x01.x, x01.y, x23.x, x23.y, x45.x, x45.y};
      const float4 wA = *(const float4*)&Ws[k * 260 + og * 8];
      const float4 wB = *(const float4*)&Ws[k * 260 + og * 8 + 4];
      const float wv[8] = {wA.x, wA.y, wA.z, wA.w, wB.x, wB.y, wB.z, wB.w};
#pragma unroll
      for (int i = 0; i < 8; ++i)
#pragma unroll
        for (int j = 0; j < 6; ++j)
          acc[i][j] = fmaf(wv[i], xv[j], acc[i][j]);
    }
    __syncthreads();
  }

  // ---- mix: two stages of 2 t each ----
  float* zs = SM;                       // [256][58]
  const int tl = pg / 9;                // 0/1 within the 54-col stage
  const int v0 = pg * 3 - tl * 27;      // 0,3,..24
  const size_t nbase = (size_t)n * CTV;

  for (int t2 = 0; t2 < 2; ++t2) {
    __syncthreads();                    // previous-phase zs readers done
    if (pg >= t2 * 9 && pg < t2 * 9 + 9) {
      const int pl = (pg - t2 * 9) * 6;
#pragma unroll
      for (int i = 0; i < 8; ++i) {
        float* zrow = &zs[(og * 8 + i) * 58 + pl];
        *(float2*)(zrow)     = make_float2(acc[i][0], acc[i][1]);
        *(float2*)(zrow + 2) = make_float2(acc[i][2], acc[i][3]);
        *(float2*)(zrow + 4) = make_float2(acc[i][4], acc[i][5]);
      }
    }
    __syncthreads();

    float y[4][3];
#pragma unroll
    for (int oi = 0; oi < 4; ++oi)
      y[oi][0] = y[oi][1] = y[oi][2] = 0.f;

    const float* a0 = &as[v0];
    const float* a1 = &as[VV * 28 + v0];
    const int ur = tl * 27;
#pragma unroll 9
    for (int u = 0; u < 27; ++u) {
      const float a00 = a0[u * 28], a01 = a0[u * 28 + 1], a02 = a0[u * 28 + 2];
      const float a10 = a1[u * 28], a11 = a1[u * 28 + 1], a12 = a1[u * 28 + 2];
#pragma unroll
      for (int oi = 0; oi < 4; ++oi) {
        const float z0 = zs[(og * 4 + oi) * 58 + ur + u];
        const float z1 = zs[(128 + og * 4 + oi) * 58 + ur + u];
        y[oi][0] = fmaf(z0, a00, fmaf(z1, a10, y[oi][0]));
        y[oi][1] = fmaf(z0, a01, fmaf(z1, a11, y[oi][1]));
        y[oi][2] = fmaf(z0, a02, fmaf(z1, a12, y[oi][2]));
      }
    }
    const int t = p0 / 27 + t2 * 2 + tl;
#pragma unroll
    for (int oi = 0; oi < 4; ++oi) {
      const int o = og * 4 + oi;
      const size_t addr = nbase + (size_t)o * TVV + (size_t)t * VV + v0;
      const float bv = bO[o];
#pragma unroll
      for (int j = 0; j < 3; ++j) {
        float val = y[oi][j] + bv + x[addr + j];
        val = val > 0.f ? val : 0.1f * val;
        y1[addr + j] = val;
      }
    }
  }
}

// ---------------- ff GEMM + residual + lrelu, fused down-proj ---------------
__global__ __launch_bounds__(256, 3) void ffdown_k(
    const float* __restrict__ y1, const float* __restrict__ wT,
    const float* __restrict__ bF, const float* __restrict__ xres,
    const float* __restrict__ wdT, const float* __restrict__ bD,
    float* __restrict__ y2, float* __restrict__ yd)
{
  __shared__ float SM[13056];   // GEMM: Xs[32][68]@0, Ws[32][132]@2176
                                // down: y2s[128][68]@0, wds[128][34]@8704
  const int n  = blockIdx.y;
  const int p0 = blockIdx.x * 64;
  const int tid = threadIdx.x;
  const int pg = tid & 15;
  const int og = tid >> 4;

  float acc[8][4];
#pragma unroll
  for (int i = 0; i < 8; ++i)
#pragma unroll
    for (int j = 0; j < 4; ++j) acc[i][j] = 0.f;

  float* Xs = SM;               // stride 68
  float* Ws = SM + 2176;        // stride 132
  const float* Xn = y1 + (size_t)n * CTV;

  for (int k0 = 0; k0 < CC; k0 += 32) {
    for (int sl = tid; sl < 512; sl += 256) {
      const int r  = sl >> 4;
      const int cc = (sl & 15) * 4;
      const int p  = p0 + cc;
      const float* src = Xn + (size_t)(k0 + r) * TVV;
      float4 val;
      if (p + 3 < TVV) {
        val = *(const float4*)(src + p);
      } else {
        val.x = (p     < TVV) ? src[p]     : 0.f;
        val.y = (p + 1 < TVV) ? src[p + 1] : 0.f;
        val.z = (p + 2 < TVV) ? src[p + 2] : 0.f;
        val.w = (p + 3 < TVV) ? src[p + 3] : 0.f;
      }
      *(float4*)&Xs[r * 68 + cc] = val;
    }
    for (int q = tid; q < 1024; q += 256) {
      const int r = q >> 5, c4 = (q & 31) * 4;
      *(float4*)&Ws[r * 132 + c4] = *(const float4*)(wT + (size_t)(k0 + r) * CC + c4);
    }
    __syncthreads();
#pragma unroll 8
    for (int k = 0; k < 32; ++k) {
      const float4 xv = *(const float4*)&Xs[k * 68 + pg * 4];
      const float4 wA = *(const float4*)&Ws[k * 132 + og * 8];
      const float4 wB = *(const float4*)&Ws[k * 132 + og * 8 + 4];
      const float wv[8] = {wA.x, wA.y, wA.z, wA.w, wB.x, wB.y, wB.z, wB.w};
#pragma unroll
      for (int i = 0; i < 8; ++i) {
        acc[i][0] = fmaf(wv[i], xv.x, acc[i][0]);
        acc[i][1] = fmaf(wv[i], xv.y, acc[i][1]);
        acc[i][2] = fmaf(wv[i], xv.z, acc[i][2]);
        acc[i][3] = fmaf(wv[i], xv.w, acc[i][3]);
      }
    }
    __syncthreads();
  }

  // epilogue: y2 = lrelu(x + acc + bF); stage y2s + wds; then down phase
  float* y2s = SM;              // [128][68]
  float* wds = SM + 8704;       // [128][34]
  const size_t nb = (size_t)n * CTV;
  const int pcol = p0 + pg * 4;

  for (int q = tid; q < 2048; q += 256) {
    const int c = q >> 4, o2 = (q & 15) * 2;
    *(float2*)&wds[c * 34 + o2] = *(const float2*)(wdT + c * 32 + o2);
  }
#pragma unroll
  for (int i = 0; i < 8; ++i) {
    const int o = og * 8 + i;
    const float bv = bF[o];
    const size_t rowoff = nb + (size_t)o * TVV;
    if (pcol + 3 < TVV) {
      const float4 rr4 = *(const float4*)(xres + rowoff + pcol);
      float4 st;
      st.x = acc[i][0] + bv + rr4.x;
      st.y = acc[i][1] + bv + rr4.y;
      st.z = acc[i][2] + bv + rr4.z;
      st.w = acc[i][3] + bv + rr4.w;
      st.x = st.x > 0.f ? st.x : 0.1f * st.x;
      st.y = st.y > 0.f ? st.y : 0.1f * st.y;
      st.z = st.z > 0.f ? st.z : 0.1f * st.z;
      st.w = st.w > 0.f ? st.w : 0.1f * st.w;
      *(float4*)(y2 + rowoff + pcol) = st;
      *(float4*)&y2s[o * 68 + pg * 4] = st;
    } else {
#pragma unroll
      for (int j = 0; j < 4; ++j) {
        const int p = pcol + j;
        float v = 0.f;
        if (p < TVV) {
          v = acc[i][j] + bv + xres[rowoff + p];
          v = v > 0.f ? v : 0.1f * v;
          y2[rowoff + p] = v;
        }
        y2s[o * 68 + pg * 4 + j] = v;
      }
    }
  }
  __syncthreads();

  // down: yd[o2][p] = lrelu(sum_c wds[c][o2] * y2s[c][p] + bD)
  float d0[4] = {0.f, 0.f, 0.f, 0.f};
  float d1[4] = {0.f, 0.f, 0.f, 0.f};
  const int o2g = og;           // 0..15 -> o2 = o2g*2+{0,1}
#pragma unroll 4
  for (int c = 0; c < CC; ++c) {
    const float4 yv = *(const float4*)&y2s[c * 68 + pg * 4];
    const float2 w  = *(const float2*)&wds[c * 34 + o2g * 2];
    d0[0] = fmaf(w.x, yv.x, d0[0]); d0[1] = fmaf(w.x, yv.y, d0[1]);
    d0[2] = fmaf(w.x, yv.z, d0[2]); d0[3] = fmaf(w.x, yv.w, d0[3]);
    d1[0] = fmaf(w.y, yv.x, d1[0]); d1[1] = fmaf(w.y, yv.y, d1[1]);
    d1[2] = fmaf(w.y, yv.z, d1[2]); d1[3] = fmaf(w.y, yv.w, d1[3]);
  }
  const size_t ydb = (size_t)n * RCC * TVV;
#pragma unroll
  for (int oi = 0; oi < 2; ++oi) {
    const int o2 = o2g * 2 + oi;
    const float bv = bD[o2];
    float* dv = oi ? d1 : d0;
    if (pcol + 3 < TVV) {
      float4 st;
      st.x = dv[0] + bv; st.y = dv[1] + bv; st.z = dv[2] + bv; st.w = dv[3] + bv;
      st.x = st.x > 0.f ? st.x : 0.1f * st.x;
      st.y = st.y > 0.f ? st.y : 0.1f * st.y;
      st.z = st.z > 0.f ? st.z : 0.1f * st.z;
      st.w = st.w > 0.f ? st.w : 0.1f * st.w;
      *(float4*)(yd + ydb + (size_t)o2 * TVV + pcol) = st;
    } else {
#pragma unroll
      for (int j = 0; j < 4; ++j) {
        const int p = pcol + j;
        if (p < TVV) {
          float v = dv[j] + bv;
          v = v > 0.f ? v : 0.1f * v;
          yd[ydb + (size_t)o2 * TVV + p] = v;
        }
      }
    }
  }
}

// ---------------- fused TCN (3 dilated dw+bn+lrelu, pw, sum) + back GEMM -----
__global__ __launch_bounds__(256, 3) void tcnback_k(
    const float* __restrict__ yd, const float* __restrict__ dws,
    const float* __restrict__ dbs, const float* __restrict__ pws,
    const float* __restrict__ bsum, const float* __restrict__ wbT,
    const float* __restrict__ bB, const float* __restrict__ y2,
    float* __restrict__ out)
{
  __shared__ float SM[12224];
  // phase A/B: Ys[32][10][27]@0 (8640), Hs[3456]@8640
  // phase C:   accs[32][4][28]@0 (3584), wbs[32][128]@3584 (4096)
  const int n  = blockIdx.y;
  const int t0 = blockIdx.x * 4;
  const int tid = threadIdx.x;
  float* Ys = SM;
  float* Hs = SM + 8640;

  const float* yb = yd + (size_t)n * RCC * TVV;
  for (int idx = tid; idx < RCC * 10 * VV; idx += 256) {
    const int c = idx / 270, rr = (idx / 27) % 10, v = idx % 27;
    const int t = t0 - 3 + rr;
    Ys[c * 270 + rr * 27 + v] =
        (t >= 0 && t < TT) ? yb[(size_t)c * TVV + (size_t)t * VV + v] : 0.f;
  }
  __syncthreads();

  float accr[14];
#pragma unroll
  for (int j = 0; j < 14; ++j) accr[j] = 0.f;

  for (int i = 0; i < 3; ++i) {
    const int d = i + 1;
    for (int idx = tid; idx < 3456; idx += 256) {
      const int c = idx / 108, rr = idx % 108, t2 = rr / 27, v = rr % 27;
      const float* w = dws + (size_t)(i * RCC + c) * 3;
      float h = dbs[i * RCC + c]
              + w[0] * Ys[c * 270 + (3 + t2 - d) * 27 + v]
              + w[1] * Ys[c * 270 + (3 + t2) * 27 + v]
              + w[2] * Ys[c * 270 + (3 + t2 + d) * 27 + v];
      Hs[idx] = h > 0.f ? h : 0.1f * h;
    }
    __syncthreads();
#pragma unroll
    for (int j = 0; j < 14; ++j) {
      const int idx = tid + j * 256;
      if (idx < 3456) {
        const int o = idx / 108, rr = idx % 108;
        const float* pwrow = pws + (size_t)(i * RCC + o) * RCC;
        float a = accr[j];
#pragma unroll 8
        for (int c = 0; c < RCC; ++c) a = fmaf(pwrow[c], Hs[c * 108 + rr], a);
        accr[j] = a;
      }
    }
    __syncthreads();
  }

  // stage accs (+bsum) and wbs (Ys region is dead now)
  float* accs = SM;             // [32][4][28]
  float* wbs  = SM + 3584;      // [32][128]
#pragma unroll
  for (int j = 0; j < 14; ++j) {
    const int idx = tid + j * 256;
    if (idx < 3456) {
      const int o = idx / 108, rr = idx % 108, t2 = rr / 27, v = rr % 27;
      accs[o * 112 + t2 * 28 + v] = accr[j] + bsum[o];
    }
  }
  for (int q = tid; q < 128; q += 256)
    accs[(q >> 2) * 112 + (q & 3) * 28 + 27] = 0.f;    // zero pads
  for (int q = tid; q < 4096; q += 256) wbs[q] = wbT[q];
  __syncthreads();

  // back phase: thread (og3 -> o = og3*2+{0,1}, tg -> t2)
  const int og3 = tid >> 2, tg = tid & 3;
  const int o0 = og3 * 2;
  float yy[2][28];
#pragma unroll
  for (int v = 0; v < 28; ++v) { yy[0][v] = 0.f; yy[1][v] = 0.f; }
#pragma unroll 4
  for (int k = 0; k < 32; ++k) {
    const float2 w = *(const float2*)&wbs[k * 128 + o0];
    const float* ar = &accs[k * 112 + tg * 28];
#pragma unroll
    for (int v4 = 0; v4 < 7; ++v4) {
      const float4 a = *(const float4*)&ar[v4 * 4];
      yy[0][v4 * 4 + 0] = fmaf(w.x, a.x, yy[0][v4 * 4 + 0]);
      yy[0][v4 * 4 + 1] = fmaf(w.x, a.y, yy[0][v4 * 4 + 1]);
      yy[0][v4 * 4 + 2] = fmaf(w.x, a.z, yy[0][v4 * 4 + 2]);
      yy[0][v4 * 4 + 3] = fmaf(w.x, a.w, yy[0][v4 * 4 + 3]);
      yy[1][v4 * 4 + 0] = fmaf(w.y, a.x, yy[1][v4 * 4 + 0]);
      yy[1][v4 * 4 + 1] = fmaf(w.y, a.y, yy[1][v4 * 4 + 1]);
      yy[1][v4 * 4 + 2] = fmaf(w.y, a.z, yy[1][v4 * 4 + 2]);
      yy[1][v4 * 4 + 3] = fmaf(w.y, a.w, yy[1][v4 * 4 + 3]);
    }
  }
  const size_t ob = (size_t)n * CTV;
  const int t = t0 + tg;
#pragma unroll
  for (int oi = 0; oi < 2; ++oi) {
    const int o = o0 + oi;
    const float bb = bB[o];
    const size_t addr = ob + (size_t)o * TVV + (size_t)t * VV;
#pragma unroll
    for (int v = 0; v < 27; ++v) {
      float val = yy[oi][v] + bb + y2[addr + v];
      val = val > 0.f ? val : 0.1f * val;
      out[addr + v] = val;
    }
  }
}

// ---------------- launch ----------------
extern "C" void kernel_launch(void* const* d_in, const int* in_sizes, int n_in,
                              void* d_out, int out_size, void* d_ws, size_t ws_size,
                              hipStream_t stream)
{
  const float* x       = (const float*)d_in[0];
  const float* in_w    = (const float*)d_in[1];
  const float* in_b    = (const float*)d_in[2];
  const float* alphas  = (const float*)d_in[3];
  const float* att0    = (const float*)d_in[4];
  const float* out_w   = (const float*)d_in[5];
  const float* out_b   = (const float*)d_in[6];
  const float* out_bn  = (const float*)d_in[7];
  const float* ff_w    = (const float*)d_in[8];
  const float* ff_b    = (const float*)d_in[9];
  const float* ff_bn   = (const float*)d_in[10];
  const float* down_w  = (const float*)d_in[11];
  const float* down_bn = (const float*)d_in[12];
  const float* dw_w    = (const float*)d_in[13];
  const float* dw_b    = (const float*)d_in[14];
  const float* bn_a    = (const float*)d_in[15];
  const float* pw_w    = (const float*)d_in[16];
  const float* bn_b    = (const float*)d_in[17];
  const float* back_w  = (const float*)d_in[18];
  const float* back_bn = (const float*)d_in[19];
  float* ws  = (float*)d_ws;
  float* out = (float*)d_out;

  // 1) fold BN, transpose weights, pos-enc table
  prep_k<<<64, 256, 0, stream>>>(in_w, out_w, out_b, out_bn, ff_w, ff_b, ff_bn,
                                 down_w, down_bn, dw_w, dw_b, bn_a, pw_w, bn_b,
                                 back_w, back_bn, ws);
  // 2) qk = in_w @ (x + pe) + in_b            -> bufA
  qkproj_k<<<dim3(169, 32), 256, 0, stream>>>(
      x, ws + OFF_WT_IN, in_b, ws + OFF_PE, ws + OFF_BUFA);
  // 3) attention gram partials + finalize     -> att
  attpart_k<<<dim3(64, 8), 256, 0, stream>>>(ws + OFF_BUFA, ws + OFF_ATTP);
  attfin_k<<<(NN * SS * VV * VV + 255) / 256, 256, 0, stream>>>(
      ws + OFF_ATTP, alphas, att0, ws + OFF_ATT);
  // 4) y1 = lrelu(x + bO + sum_s (W'_s x) att_s)  -> d_out  (fused z-GEMM + mix)
  zmix_k<<<dim3(100, 32), 576, 0, stream>>>(
      x, ws + OFF_WS_OUT, ws + OFF_ATT, ws + OFF_B_OUT, out);
  // 5) y2 = lrelu(x + ff@y1 + bF) -> bufA; yd = lrelu(down@y2 + bD) -> ws[yd]
  ffdown_k<<<dim3(169, 32), 256, 0, stream>>>(
      out, ws + OFF_WT_FF, ws + OFF_B_FF, x, ws + OFF_WT_DOWN, ws + OFF_B_DOWN,
      ws + OFF_BUFA, ws + OFF_YD);
  // 6) TCN (3 branches) + back GEMM + y2 residual + lrelu -> d_out
  tcnback_k<<<dim3(100, 32), 256, 0, stream>>>(
      ws + OFF_YD, ws + OFF_DWS, ws + OFF_DBS, ws + OFF_PWS, ws + OFF_BSUM,
      ws + OFF_WT_BACK, ws + OFF_B_BACK, ws + OFF_BUFA, out);
}